// Round 4
// baseline (339.178 us; speedup 1.0000x reference)
//
#include <hip/hip_runtime.h>
#include <cmath>

// Decoder: 3-layer GRU (B=16, H=2048, E=128) + vocab projection (V=32000) + log_softmax.
// Memory-bound: 516 MB fp32 weights streamed once. Roofline ~78us @ ~6.8 TB/s.
//
// Round-3 lesson: pairing every 1KB W-load with 16 ds_reads made the per-CU LDS
// pipe the bottleneck (16 KB LDS per KB W). This version amortizes: each
// rg-group owns R rows, so one set of 16 x-reads serves R KB of W, and x is
// read from L2 (no LDS, no barriers, 8 waves/CU). x-read = 256B contiguous,
// 4-way lane duplication collapsed by the coalescer -> x L2 traffic == W rate.
// k-split=2 partial sums make units == waves exactly (512 blocks x 4 waves).

#define BB 16
#define HH 2048
#define EE 128
#define VV 32000
#define G3H (3 * HH)
#define PSTRIDE (BB * G3H)   // one k-partial plane

__device__ __forceinline__ void fma4(float& a, const float4 w, const float4 x) {
  a = fmaf(w.x, x.x, a); a = fmaf(w.y, x.y, a);
  a = fmaf(w.z, x.z, a); a = fmaf(w.w, x.w, a);
}

// static-index select (15 cndmask; no runtime-indexed register arrays)
__device__ __forceinline__ float sel16(const float a[16], int i) {
  float s0 = (i & 1) ? a[1]  : a[0];
  float s1 = (i & 1) ? a[3]  : a[2];
  float s2 = (i & 1) ? a[5]  : a[4];
  float s3 = (i & 1) ? a[7]  : a[6];
  float s4 = (i & 1) ? a[9]  : a[8];
  float s5 = (i & 1) ? a[11] : a[10];
  float s6 = (i & 1) ? a[13] : a[12];
  float s7 = (i & 1) ? a[15] : a[14];
  float t0 = (i & 2) ? s1 : s0;
  float t1 = (i & 2) ? s3 : s2;
  float t2 = (i & 2) ? s5 : s4;
  float t3 = (i & 2) ? s7 : s6;
  float u0 = (i & 4) ? t1 : t0;
  float u1 = (i & 4) ? t3 : t2;
  return (i & 8) ? u1 : u0;
}

// 12-row x half-k GEMV unit. Lane = kk(16) x rg(4); rg owns rows row0..row0+2.
// Writes the k-partial dot for (batch kk, 3 rows) into dst[b][row].
template<int DIM, bool EMB>
__device__ __forceinline__
void gemv12(const float* __restrict__ x, const int* __restrict__ tokens,
            const float* __restrict__ W, float* __restrict__ dst,
            int ru, int ks, int kk, int rg)
{
  constexpr int KH = DIM / 2;                 // half-k range
  const int koff = ks * KH;
  const int row0 = ru * 12 + rg * 3;
  const float* W0 = W + (size_t)row0 * DIM + koff;
  const float* W1 = W0 + DIM;
  const float* W2 = W1 + DIM;

  float acc[3][16] = {};
  #pragma unroll 2
  for (int it = 0; it < KH / 64; ++it) {
    const int k = it * 64 + kk * 4;
    const float4 w0 = *(const float4*)(W0 + k);
    const float4 w1 = *(const float4*)(W1 + k);
    const float4 w2 = *(const float4*)(W2 + k);
    #pragma unroll
    for (int b = 0; b < 16; ++b) {
      float4 xv;
      if (EMB) {
        xv = *(const float4*)(x + (size_t)tokens[b] * DIM + koff + k);
        xv.x = fmaxf(xv.x, 0.f); xv.y = fmaxf(xv.y, 0.f);
        xv.z = fmaxf(xv.z, 0.f); xv.w = fmaxf(xv.w, 0.f);
      } else {
        xv = *(const float4*)(x + (size_t)b * DIM + koff + k);
      }
      fma4(acc[0][b], w0, xv);
      fma4(acc[1][b], w1, xv);
      fma4(acc[2][b], w2, xv);
    }
  }

  #pragma unroll
  for (int r = 0; r < 3; ++r) {
    #pragma unroll
    for (int b = 0; b < 16; ++b) {
      float a = acc[r][b];
      a += __shfl_xor(a, 1, 64);
      a += __shfl_xor(a, 2, 64);
      a += __shfl_xor(a, 4, 64);
      a += __shfl_xor(a, 8, 64);
      acc[r][b] = a;
    }
  }
  #pragma unroll
  for (int r = 0; r < 3; ++r)
    dst[(size_t)kk * G3H + row0 + r] = sel16(acc[r], kk);
}

// One GRU layer's two GEMVs. 512 blocks x 256 thr = 2048 waves = 2048 units:
// waves [0,1024): gi = x @ W_ih.T (k-split 2); waves [1024,2048): gh = h @ W_hh.T.
template<int DIMI, bool EMB>
__global__ __launch_bounds__(256, 2)
void gru_gemv(const float* __restrict__ xsrc, const int* __restrict__ tokens,
              const float* __restrict__ hprev,
              const float* __restrict__ Wih, const float* __restrict__ Whh,
              float* __restrict__ giP,   // [2][B][3H] k-partials
              float* __restrict__ ghP)   // [2][B][3H]
{
  const int tid = threadIdx.x;
  const int kk  = tid & 15;
  const int rg  = (tid >> 4) & 3;
  const int wid = blockIdx.x * 4 + (tid >> 6);
  if (wid < 1024) {
    const int ru = wid >> 1, ks = wid & 1;
    gemv12<DIMI, EMB>(xsrc, tokens, Wih, giP + (size_t)ks * PSTRIDE, ru, ks, kk, rg);
  } else {
    const int u = wid - 1024;
    const int ru = u >> 1, ks = u & 1;
    gemv12<HH, false>(hprev, nullptr, Whh, ghP + (size_t)ks * PSTRIDE, ru, ks, kk, rg);
  }
}

// Gate math: sum k-partials, add biases, h' = (1-z)*n + z*h. B*H threads.
__global__ __launch_bounds__(256)
void gru_epi(const float* __restrict__ giP, const float* __restrict__ ghP,
             const float* __restrict__ bih, const float* __restrict__ bhh,
             const float* __restrict__ hprev, float* __restrict__ hout)
{
  const int idx = blockIdx.x * 256 + threadIdx.x;
  const int j = idx & (HH - 1);
  const size_t base = (size_t)(idx >> 11) * G3H;
  const float ir  = giP[base + j]          + giP[PSTRIDE + base + j]          + bih[j];
  const float iz  = giP[base + HH + j]     + giP[PSTRIDE + base + HH + j]     + bih[HH + j];
  const float in_ = giP[base + 2 * HH + j] + giP[PSTRIDE + base + 2 * HH + j] + bih[2 * HH + j];
  const float hr  = ghP[base + j]          + ghP[PSTRIDE + base + j]          + bhh[j];
  const float hz  = ghP[base + HH + j]     + ghP[PSTRIDE + base + HH + j]     + bhh[HH + j];
  const float hn  = ghP[base + 2 * HH + j] + ghP[PSTRIDE + base + 2 * HH + j] + bhh[2 * HH + j];
  const float r = 1.f / (1.f + expf(-(ir + hr)));
  const float z = 1.f / (1.f + expf(-(iz + hz)));
  const float n = tanhf(in_ + r * hn);
  hout[idx] = (1.f - z) * n + z * hprev[idx];
}

// Vocab projection: wave = 16 rows (rg owns 4), full k. 500 blocks = 2000 units.
__global__ __launch_bounds__(256, 2)
void out_kernel(const float* __restrict__ h2, const float* __restrict__ Wout,
                const float* __restrict__ bout, float* __restrict__ logits)
{
  const int tid = threadIdx.x;
  const int kk  = tid & 15;
  const int rg  = (tid >> 4) & 3;
  const int wid = blockIdx.x * 4 + (tid >> 6);
  const int row0 = wid * 16 + rg * 4;

  const float* W0 = Wout + (size_t)row0 * HH;
  const float* W1 = W0 + HH;
  const float* W2 = W1 + HH;
  const float* W3 = W2 + HH;

  float acc[4][16] = {};
  #pragma unroll 2
  for (int it = 0; it < HH / 64; ++it) {
    const int k = it * 64 + kk * 4;
    const float4 w0 = *(const float4*)(W0 + k);
    const float4 w1 = *(const float4*)(W1 + k);
    const float4 w2 = *(const float4*)(W2 + k);
    const float4 w3 = *(const float4*)(W3 + k);
    #pragma unroll
    for (int b = 0; b < 16; ++b) {
      const float4 xv = *(const float4*)(h2 + (size_t)b * HH + k);
      fma4(acc[0][b], w0, xv);
      fma4(acc[1][b], w1, xv);
      fma4(acc[2][b], w2, xv);
      fma4(acc[3][b], w3, xv);
    }
  }

  #pragma unroll
  for (int r = 0; r < 4; ++r) {
    #pragma unroll
    for (int b = 0; b < 16; ++b) {
      float a = acc[r][b];
      a += __shfl_xor(a, 1, 64);
      a += __shfl_xor(a, 2, 64);
      a += __shfl_xor(a, 4, 64);
      a += __shfl_xor(a, 8, 64);
      acc[r][b] = a;
    }
  }

  const float4 bo = *(const float4*)(bout + row0);
  float4 o;
  o.x = sel16(acc[0], kk) + bo.x;
  o.y = sel16(acc[1], kk) + bo.y;
  o.z = sel16(acc[2], kk) + bo.z;
  o.w = sel16(acc[3], kk) + bo.w;
  *(float4*)(logits + (size_t)kk * VV + row0) = o;
}

// In-place log_softmax over each of the 16 rows (32000 wide).
__global__ __launch_bounds__(1024)
void lsm_kernel(float* __restrict__ logp)
{
  const int b   = blockIdx.x;
  const int tid = threadIdx.x;
  float* row = logp + (size_t)b * VV;
  const float4* r4 = (const float4*)row;
  __shared__ float red[16];
  const int wv = tid >> 6, ln = tid & 63;

  float m = -3.4e38f;
  for (int i = tid; i < VV / 4; i += 1024) {
    float4 v = r4[i];
    m = fmaxf(m, fmaxf(fmaxf(v.x, v.y), fmaxf(v.z, v.w)));
  }
  #pragma unroll
  for (int s = 1; s < 64; s <<= 1) m = fmaxf(m, __shfl_xor(m, s, 64));
  if (ln == 0) red[wv] = m;
  __syncthreads();
  if (tid == 0) {
    float mm = red[0];
    for (int w = 1; w < 16; ++w) mm = fmaxf(mm, red[w]);
    red[0] = mm;
  }
  __syncthreads();
  const float M = red[0];
  __syncthreads();

  float s = 0.f;
  for (int i = tid; i < VV / 4; i += 1024) {
    float4 v = r4[i];
    s += expf(v.x - M) + expf(v.y - M) + expf(v.z - M) + expf(v.w - M);
  }
  #pragma unroll
  for (int t = 1; t < 64; t <<= 1) s += __shfl_xor(s, t, 64);
  if (ln == 0) red[wv] = s;
  __syncthreads();
  if (tid == 0) {
    float ss = 0.f;
    for (int w = 0; w < 16; ++w) ss += red[w];
    red[0] = M + logf(ss);
  }
  __syncthreads();
  const float L = red[0];

  float4* w4 = (float4*)row;
  for (int i = tid; i < VV / 4; i += 1024) {
    float4 v = r4[i];
    v.x -= L; v.y -= L; v.z -= L; v.w -= L;
    w4[i] = v;
  }
}

extern "C" void kernel_launch(void* const* d_in, const int* in_sizes, int n_in,
                              void* d_out, int out_size, void* d_ws, size_t ws_size,
                              hipStream_t stream)
{
  const int*   tokens = (const int*)d_in[0];
  const float* hidden = (const float*)d_in[1]; // (3,B,H)
  const float* emb    = (const float*)d_in[2]; // (V,E)
  const float* Wih0 = (const float*)d_in[3];
  const float* Whh0 = (const float*)d_in[4];
  const float* bih0 = (const float*)d_in[5];
  const float* bhh0 = (const float*)d_in[6];
  const float* Wih1 = (const float*)d_in[7];
  const float* Whh1 = (const float*)d_in[8];
  const float* bih1 = (const float*)d_in[9];
  const float* bhh1 = (const float*)d_in[10];
  const float* Wih2 = (const float*)d_in[11];
  const float* Whh2 = (const float*)d_in[12];
  const float* bih2 = (const float*)d_in[13];
  const float* bhh2 = (const float*)d_in[14];
  const float* Wout = (const float*)d_in[15];
  const float* bout = (const float*)d_in[16];

  float* outp = (float*)d_out;
  float* logp = outp;                       // (B,V)
  float* hnew = outp + (size_t)BB * VV;     // (3,B,H)
  float* h0 = hnew;
  float* h1 = hnew + BB * HH;
  float* h2 = hnew + 2 * BB * HH;

  float* giP = (float*)d_ws;                // [2][B][3H]
  float* ghP = giP + 2 * (size_t)PSTRIDE;   // [2][B][3H]

  gru_gemv<EE, true ><<<512, 256, 0, stream>>>(emb, tokens, hidden, Wih0, Whh0, giP, ghP);
  gru_epi<<<128, 256, 0, stream>>>(giP, ghP, bih0, bhh0, hidden, h0);
  gru_gemv<HH, false><<<512, 256, 0, stream>>>(h0, nullptr, hidden + BB * HH, Wih1, Whh1, giP, ghP);
  gru_epi<<<128, 256, 0, stream>>>(giP, ghP, bih1, bhh1, hidden + BB * HH, h1);
  gru_gemv<HH, false><<<512, 256, 0, stream>>>(h1, nullptr, hidden + 2 * BB * HH, Wih2, Whh2, giP, ghP);
  gru_epi<<<128, 256, 0, stream>>>(giP, ghP, bih2, bhh2, hidden + 2 * BB * HH, h2);
  out_kernel<<<500, 256, 0, stream>>>(h2, Wout, bout, logp);
  lsm_kernel<<<16, 1024, 0, stream>>>(logp);
}